// Round 5
// baseline (746.796 us; speedup 1.0000x reference)
//
#include <hip/hip_runtime.h>

#define NUM_SYM 50000
#define NUM_HERB 50000
#define N_NODES (NUM_SYM + NUM_HERB)
#define DIM 128
#define LL_END 0x3FFFFF   // 22-bit sentinel; valid edge indices < 2^22
#define SCAN_BS 1024

__device__ __forceinline__ float bf2f(unsigned short u) {
    return __uint_as_float((unsigned)u << 16);
}
__device__ __forceinline__ unsigned short f2bf(float f) {
    unsigned u = __float_as_uint(f);
    unsigned r = (u + 0x7FFFu + ((u >> 16) & 1u)) >> 16;   // round-to-nearest-even
    return (unsigned short)r;
}

// ---------------- bf16 staging of the gather table ----------------
__global__ __launch_bounds__(256) void to_bf16(
    const float* __restrict__ sym, const float* __restrict__ herb,
    ushort* __restrict__ xbf)
{
    int i = blockIdx.x * 256 + threadIdx.x;          // float4 index
    const int n4 = N_NODES * DIM / 4;
    if (i >= n4) return;
    const int sym4 = NUM_SYM * DIM / 4;
    float4 v = (i < sym4) ? reinterpret_cast<const float4*>(sym)[i]
                          : reinterpret_cast<const float4*>(herb)[i - sym4];
    ushort4 o;
    o.x = f2bf(v.x); o.y = f2bf(v.y); o.z = f2bf(v.z); o.w = f2bf(v.w);
    reinterpret_cast<ushort4*>(xbf)[i] = o;
}

// ---------------- linked-list build (+ fused row histogram) ----------------
__global__ __launch_bounds__(256) void init_head(int* __restrict__ head)
{
    int i = blockIdx.x * 256 + threadIdx.x;
    if (i < N_NODES) head[i] = LL_END;
}

// Node packing (int2):
//   x = (next << 10) | (col >> 7)          next: 22 bits, col high 10 of 17
//   y = (valbits & ~0x7F) | (col & 0x7F)   fp32 val, low 7 mantissa bits = col low
__global__ __launch_bounds__(256) void build_ll(
    const int* __restrict__ rows, const int* __restrict__ cols,
    const float* __restrict__ vals, int E,
    int* __restrict__ head, int* __restrict__ counts, int2* __restrict__ ll)
{
    int e = blockIdx.x * 256 + threadIdx.x;
    if (e >= E) return;
    int r = rows[e];
    int c = cols[e];
    unsigned vb = (unsigned)__float_as_int(vals[e]);
    int old = atomicExch(&head[r], e);          // device-scope, cross-XCD safe
    atomicAdd(&counts[r], 1);
    int2 nd;
    nd.x = (int)(((unsigned)old << 10) | ((unsigned)c >> 7));
    nd.y = (int)((vb & ~0x7Fu) | ((unsigned)c & 0x7Fu));
    ll[e] = nd;                                  // sequential, coalesced
}

// ---------------- scan (counts -> exclusive rowptr) ----------------
__global__ __launch_bounds__(SCAN_BS) void scan_a(
    const int* __restrict__ counts, int* __restrict__ excl,
    int* __restrict__ blocksums)
{
    __shared__ int s[SCAN_BS];
    int t = threadIdx.x;
    int i = blockIdx.x * SCAN_BS + t;
    int v = (i < N_NODES) ? counts[i] : 0;
    s[t] = v;
    __syncthreads();
    for (int off = 1; off < SCAN_BS; off <<= 1) {
        int x = (t >= off) ? s[t - off] : 0;
        __syncthreads();
        s[t] += x;
        __syncthreads();
    }
    if (i < N_NODES) excl[i] = s[t] - v;
    if (t == SCAN_BS - 1) blocksums[blockIdx.x] = s[t];
}

__global__ __launch_bounds__(128) void scan_b(int* __restrict__ blocksums, int nb)
{
    __shared__ int s[128];
    int t = threadIdx.x;
    int v = (t < nb) ? blocksums[t] : 0;
    s[t] = v;
    __syncthreads();
    for (int off = 1; off < 128; off <<= 1) {
        int x = (t >= off) ? s[t - off] : 0;
        __syncthreads();
        s[t] += x;
        __syncthreads();
    }
    if (t < nb) blocksums[t] = s[t] - v;   // exclusive
}

__global__ __launch_bounds__(SCAN_BS) void scan_c(
    int* __restrict__ rowptr, const int* __restrict__ blocksums)
{
    int i = blockIdx.x * SCAN_BS + threadIdx.x;
    if (i < N_NODES) rowptr[i] += blocksums[blockIdx.x];
}

// ---------------- LL -> CSR compaction ----------------
// One thread per row; consecutive threads write consecutive row ranges, so
// stores coalesce in L2 (write amp ~1). Chain read traffic paid ONCE here.
__global__ __launch_bounds__(256) void compact_csr(
    const int* __restrict__ head, const int* __restrict__ rowptr,
    const int2* __restrict__ ll, int2* __restrict__ csr)
{
    int r = blockIdx.x * 256 + threadIdx.x;
    if (r >= N_NODES) return;
    unsigned e = (unsigned)head[r];
    int j = rowptr[r];
    while (e != LL_END) {
        int2 nd = ll[e];
        unsigned x0 = (unsigned)nd.x;
        unsigned y0 = (unsigned)nd.y;
        unsigned col = ((x0 & 0x3FFu) << 7) | (y0 & 0x7Fu);
        csr[j++] = make_int2((int)col, (int)(y0 & ~0x7Fu));   // clean {col, val}
        e = x0 >> 10;
    }
}

// ---------------- pull-mode SpMM over CSR, bf16 gathers ----------
// 2 rows per wave: lanes 0-31 -> row 2w, lanes 32-63 -> row 2w+1.
// Records are sequential -> no pointer-chase dependency; loads pipeline.
template <bool FUSE_MEAN>
__global__ __launch_bounds__(256) void spmm_csr_bf16(
    const int2* __restrict__ csr, const int* __restrict__ rowptr, int E,
    const ushort* __restrict__ xbf,              // gather table [N, DIM] bf16
    const float* __restrict__ sym, const float* __restrict__ herb,
    const ushort* __restrict__ e1bf,             // layer-1 result (FUSE only)
    void* __restrict__ outp)
{
    int wave = blockIdx.x * 4 + (threadIdx.x >> 6);
    int half = (threadIdx.x >> 5) & 1;
    int lane = threadIdx.x & 31;
    int r = wave * 2 + half;
    if (r >= N_NODES) return;

    int j   = rowptr[r];
    int end = (r + 1 < N_NODES) ? rowptr[r + 1] : E;

    float4 acc = make_float4(0.f, 0.f, 0.f, 0.f);
    for (; j + 1 < end; j += 2) {
        int2 r0 = csr[j];
        int2 r1 = csr[j + 1];
        float v0 = __int_as_float(r0.y);
        float v1 = __int_as_float(r1.y);
        ushort4 m0 = reinterpret_cast<const ushort4*>(xbf + (size_t)r0.x * DIM)[lane];
        ushort4 m1 = reinterpret_cast<const ushort4*>(xbf + (size_t)r1.x * DIM)[lane];
        acc.x += v0 * bf2f(m0.x) + v1 * bf2f(m1.x);
        acc.y += v0 * bf2f(m0.y) + v1 * bf2f(m1.y);
        acc.z += v0 * bf2f(m0.z) + v1 * bf2f(m1.z);
        acc.w += v0 * bf2f(m0.w) + v1 * bf2f(m1.w);
    }
    if (j < end) {
        int2 r0 = csr[j];
        float v0 = __int_as_float(r0.y);
        ushort4 m0 = reinterpret_cast<const ushort4*>(xbf + (size_t)r0.x * DIM)[lane];
        acc.x += v0 * bf2f(m0.x);
        acc.y += v0 * bf2f(m0.y);
        acc.z += v0 * bf2f(m0.z);
        acc.w += v0 * bf2f(m0.w);
    }

    if (FUSE_MEAN) {
        // out = (ego + e1 + acc) / 3, fp32 store
        const float4* egorow = (r < NUM_SYM)
            ? reinterpret_cast<const float4*>(sym  + (size_t)r * DIM)
            : reinterpret_cast<const float4*>(herb + (size_t)(r - NUM_SYM) * DIM);
        float4 g = egorow[lane];
        ushort4 a = reinterpret_cast<const ushort4*>(e1bf + (size_t)r * DIM)[lane];
        const float s = 1.0f / 3.0f;
        acc.x = (g.x + bf2f(a.x) + acc.x) * s;
        acc.y = (g.y + bf2f(a.y) + acc.y) * s;
        acc.z = (g.z + bf2f(a.z) + acc.z) * s;
        acc.w = (g.w + bf2f(a.w) + acc.w) * s;
        reinterpret_cast<float4*>((float*)outp + (size_t)r * DIM)[lane] = acc;
    } else {
        ushort4 o;
        o.x = f2bf(acc.x); o.y = f2bf(acc.y); o.z = f2bf(acc.z); o.w = f2bf(acc.w);
        reinterpret_cast<ushort4*>((ushort*)outp + (size_t)r * DIM)[lane] = o;
    }
}

// ---------------- fallback (round-1 verified atomic path) ----------------
__global__ __launch_bounds__(256) void spmm_scatter(
    const int* __restrict__ rows, const int* __restrict__ cols,
    const float* __restrict__ vals, int n_edges,
    const float* __restrict__ xa, const float* __restrict__ xb,
    float* __restrict__ out)
{
    int gid = blockIdx.x * 256 + threadIdx.x;
    int edge = gid >> 5;
    if (edge >= n_edges) return;
    int sub = gid & 31;
    int c = cols[edge];
    int r = rows[edge];
    float v = vals[edge];
    const float* xrow = (c < NUM_SYM) ? (xa + (size_t)c * DIM)
                                      : (xb + (size_t)(c - NUM_SYM) * DIM);
    float4 m = reinterpret_cast<const float4*>(xrow)[sub];
    float* o = out + (size_t)r * DIM + (size_t)sub * 4;
    unsafeAtomicAdd(o + 0, v * m.x);
    unsafeAtomicAdd(o + 1, v * m.y);
    unsafeAtomicAdd(o + 2, v * m.z);
    unsafeAtomicAdd(o + 3, v * m.w);
}

__global__ __launch_bounds__(256) void finalize_mean(
    const float* __restrict__ sym, const float* __restrict__ herb,
    const float* __restrict__ e1, float* __restrict__ out)
{
    int i = blockIdx.x * 256 + threadIdx.x;
    const int n4 = N_NODES * DIM / 4;
    if (i >= n4) return;
    const int sym4 = NUM_SYM * DIM / 4;
    float4 e = (i < sym4) ? reinterpret_cast<const float4*>(sym)[i]
                          : reinterpret_cast<const float4*>(herb)[i - sym4];
    float4 a = reinterpret_cast<const float4*>(e1)[i];
    float4 b = reinterpret_cast<float4*>(out)[i];
    const float s = 1.0f / 3.0f;
    float4 r;
    r.x = (e.x + a.x + b.x) * s;
    r.y = (e.y + a.y + b.y) * s;
    r.z = (e.z + a.z + b.z) * s;
    r.w = (e.w + a.w + b.w) * s;
    reinterpret_cast<float4*>(out)[i] = r;
}

extern "C" void kernel_launch(void* const* d_in, const int* in_sizes, int n_in,
                              void* d_out, int out_size, void* d_ws, size_t ws_size,
                              hipStream_t stream) {
    const float* sym  = (const float*)d_in[0];
    const float* herb = (const float*)d_in[1];
    const int*   rows = (const int*)d_in[2];
    const int*   cols = (const int*)d_in[3];
    const float* vals = (const float*)d_in[4];
    const int E = in_sizes[2];
    float* out = (float*)d_out;

    // workspace layout:
    //   xbf [25.6MB] | csr [E*8] | counts [400KB] | rowptr [400KB] |
    //   head [400KB] | bsums [4KB] | ll (reused as e1bf after compaction) [E*8 / 25.6MB]
    char* ws = (char*)d_ws;
    auto align256 = [](size_t x) { return (x + 255) & ~(size_t)255; };
    const size_t xbf_bytes  = (size_t)N_NODES * DIM * sizeof(ushort);   // 25.6 MB
    const size_t csr_off    = align256(xbf_bytes);
    const size_t counts_off = align256(csr_off + (size_t)E * 8);
    const size_t rowptr_off = align256(counts_off + (size_t)N_NODES * 4);
    const size_t head_off   = align256(rowptr_off + (size_t)N_NODES * 4);
    const size_t bsums_off  = align256(head_off + (size_t)N_NODES * 4);
    const size_t ll_off     = align256(bsums_off + 4096);
    const size_t ll_bytes   = (size_t)E * 8 > xbf_bytes ? (size_t)E * 8 : xbf_bytes;
    const size_t required   = ll_off + ll_bytes;

    if (ws_size < required || E >= (1 << 22)) {
        // fallback: verified round-1 atomic-scatter path (needs only 51.2MB e1)
        float* e1 = (float*)ws;
        const size_t e1_bytes = (size_t)N_NODES * DIM * sizeof(float);
        hipMemsetAsync(e1, 0, e1_bytes, stream);
        hipMemsetAsync(out, 0, e1_bytes, stream);
        const int spmm_blocks = (E * 32 + 255) / 256;
        spmm_scatter<<<spmm_blocks, 256, 0, stream>>>(rows, cols, vals, E, sym, herb, e1);
        spmm_scatter<<<spmm_blocks, 256, 0, stream>>>(rows, cols, vals, E,
                                                      e1, e1 + (size_t)NUM_SYM * DIM, out);
        const int n4 = N_NODES * DIM / 4;
        finalize_mean<<<(n4 + 255) / 256, 256, 0, stream>>>(sym, herb, e1, out);
        return;
    }

    ushort* xbf    = (ushort*)ws;
    int2*   csr    = (int2*)(ws + csr_off);
    int*    counts = (int*)(ws + counts_off);
    int*    rowptr = (int*)(ws + rowptr_off);
    int*    head   = (int*)(ws + head_off);
    int*    bsums  = (int*)(ws + bsums_off);
    int2*   ll     = (int2*)(ws + ll_off);
    ushort* e1bf   = (ushort*)(ws + ll_off);     // aliases ll (dead after compact)

    // --- build LL + histogram ---
    hipMemsetAsync(counts, 0, (size_t)N_NODES * 4, stream);
    init_head<<<(N_NODES + 255) / 256, 256, 0, stream>>>(head);
    build_ll<<<(E + 255) / 256, 256, 0, stream>>>(rows, cols, vals, E, head, counts, ll);

    // --- rowptr = exclusive_scan(counts) ---
    const int NB = (N_NODES + SCAN_BS - 1) / SCAN_BS;   // 98
    scan_a<<<NB, SCAN_BS, 0, stream>>>(counts, rowptr, bsums);
    scan_b<<<1, 128, 0, stream>>>(bsums, NB);
    scan_c<<<NB, SCAN_BS, 0, stream>>>(rowptr, bsums);

    // --- LL -> CSR ---
    compact_csr<<<(N_NODES + 255) / 256, 256, 0, stream>>>(head, rowptr, ll, csr);

    // --- bf16 gather table ---
    const int n4 = N_NODES * DIM / 4;
    to_bf16<<<(n4 + 255) / 256, 256, 0, stream>>>(sym, herb, xbf);

    // --- 2 propagation layers (pull over CSR) ---
    const int blocks = (N_NODES / 2 + 3) / 4;   // 2 rows/wave, 4 waves/block
    spmm_csr_bf16<false><<<blocks, 256, 0, stream>>>(csr, rowptr, E, xbf,
                                                     nullptr, nullptr, nullptr, e1bf);
    spmm_csr_bf16<true><<<blocks, 256, 0, stream>>>(csr, rowptr, E, e1bf,
                                                    sym, herb, e1bf, out);
}

// Round 6
// 513.532 us; speedup vs baseline: 1.4542x; 1.4542x over previous
//
#include <hip/hip_runtime.h>

#define NUM_SYM 50000
#define NUM_HERB 50000
#define N_NODES (NUM_SYM + NUM_HERB)
#define DIM 128
#define NB_BUCKETS ((N_NODES + 255) / 256)   // 391 coarse buckets of 256 rows
#define CHUNK 8192                           // edges per block in bucket passes

__device__ __forceinline__ float bf2f(unsigned short u) {
    return __uint_as_float((unsigned)u << 16);
}
__device__ __forceinline__ unsigned short f2bf(float f) {
    unsigned u = __float_as_uint(f);
    unsigned r = (u + 0x7FFFu + ((u >> 16) & 1u)) >> 16;   // round-to-nearest-even
    return (unsigned short)r;
}

// ---------------- bf16 staging of the gather table ----------------
__global__ __launch_bounds__(256) void to_bf16(
    const float* __restrict__ sym, const float* __restrict__ herb,
    ushort* __restrict__ xbf)
{
    int i = blockIdx.x * 256 + threadIdx.x;          // float4 index
    const int n4 = N_NODES * DIM / 4;
    if (i >= n4) return;
    const int sym4 = NUM_SYM * DIM / 4;
    float4 v = (i < sym4) ? reinterpret_cast<const float4*>(sym)[i]
                          : reinterpret_cast<const float4*>(herb)[i - sym4];
    ushort4 o;
    o.x = f2bf(v.x); o.y = f2bf(v.y); o.z = f2bf(v.z); o.w = f2bf(v.w);
    reinterpret_cast<ushort4*>(xbf)[i] = o;
}

// ---------------- two-level bucket sort (row-sorted CSR, no LL) ------------

// k1: coarse histogram, LDS-privatized (global atomics: <=391 per block)
__global__ __launch_bounds__(256) void hist_buckets(
    const int* __restrict__ rows, int E, int* __restrict__ bucket_cnt)
{
    __shared__ int h[NB_BUCKETS];
    for (int i = threadIdx.x; i < NB_BUCKETS; i += 256) h[i] = 0;
    __syncthreads();
    int start = blockIdx.x * CHUNK;
    int end   = min(start + CHUNK, E);
    for (int e = start + threadIdx.x; e < end; e += 256)
        atomicAdd(&h[rows[e] >> 8], 1);
    __syncthreads();
    for (int i = threadIdx.x; i < NB_BUCKETS; i += 256)
        if (h[i]) atomicAdd(&bucket_cnt[i], h[i]);
}

// k2: scan 391 bucket counts -> offsets [0..NB_BUCKETS] and working cursor
__global__ __launch_bounds__(512) void scan_buckets(
    const int* __restrict__ cnt, int* __restrict__ off, int* __restrict__ cursor)
{
    __shared__ int s[512];
    int t = threadIdx.x;
    int v = (t < NB_BUCKETS) ? cnt[t] : 0;
    s[t] = v;
    __syncthreads();
    for (int o = 1; o < 512; o <<= 1) {
        int x = (t >= o) ? s[t - o] : 0;
        __syncthreads();
        s[t] += x;
        __syncthreads();
    }
    if (t < NB_BUCKETS) { off[t] = s[t] - v; cursor[t] = s[t] - v; }
    if (t == NB_BUCKETS - 1) off[NB_BUCKETS] = s[t];
}

// k3: scatter edges into coarse buckets. One global atomicAdd per
// (block,bucket) reserves a contiguous range; records land in ~170B runs.
// Record packing: x = (row_low8 << 17) | col,  y = fp32 val bits.
__global__ __launch_bounds__(256) void scatter_buckets(
    const int* __restrict__ rows, const int* __restrict__ cols,
    const float* __restrict__ vals, int E,
    int* __restrict__ cursor, int2* __restrict__ bucketed)
{
    __shared__ int lh[NB_BUCKETS];
    __shared__ int lbase[NB_BUCKETS];
    for (int i = threadIdx.x; i < NB_BUCKETS; i += 256) lh[i] = 0;
    __syncthreads();
    int start = blockIdx.x * CHUNK;
    int end   = min(start + CHUNK, E);
    for (int e = start + threadIdx.x; e < end; e += 256)
        atomicAdd(&lh[rows[e] >> 8], 1);
    __syncthreads();
    for (int i = threadIdx.x; i < NB_BUCKETS; i += 256) {
        int c = lh[i];
        lbase[i] = c ? atomicAdd(&cursor[i], c) : 0;
        lh[i] = 0;                               // reuse as local cursor
    }
    __syncthreads();
    for (int e = start + threadIdx.x; e < end; e += 256) {
        int r = rows[e];
        int key = r >> 8;
        int pos = lbase[key] + atomicAdd(&lh[key], 1);
        bucketed[pos] = make_int2(((r & 255) << 17) | cols[e],
                                  __float_as_int(vals[e]));
    }
}

// k4: one block per bucket -> row-sorted CSR + rowptr. All staging in LDS;
// scatter writes confined to the bucket's ~64KB window (L2-absorbed).
__global__ __launch_bounds__(256) void bucket_to_csr(
    const int2* __restrict__ bucketed, const int* __restrict__ off,
    int2* __restrict__ csr, int* __restrict__ rowptr)
{
    __shared__ int h[256];
    int b = blockIdx.x, t = threadIdx.x;
    int s0 = off[b], s1 = off[b + 1];
    h[t] = 0;
    __syncthreads();
    for (int j = s0 + t; j < s1; j += 256)
        atomicAdd(&h[(unsigned)bucketed[j].x >> 17], 1);
    __syncthreads();
    int v = h[t];
    for (int o = 1; o < 256; o <<= 1) {          // inclusive scan in LDS
        int x = (t >= o) ? h[t - o] : 0;
        __syncthreads();
        h[t] += x;
        __syncthreads();
    }
    int excl = h[t] - v;
    int r = b * 256 + t;
    if (r < N_NODES) rowptr[r] = s0 + excl;
    __syncthreads();
    h[t] = excl;                                 // local cursor
    __syncthreads();
    for (int j = s0 + t; j < s1; j += 256) {
        int2 rec = bucketed[j];
        int key = (unsigned)rec.x >> 17;
        int pos = s0 + atomicAdd(&h[key], 1);
        csr[pos] = make_int2(rec.x & 0x1FFFF, rec.y);   // clean {col, val}
    }
}

// ---------------- pull-mode SpMM over CSR, bf16 gathers ----------
// 2 rows per wave: lanes 0-31 -> row 2w, lanes 32-63 -> row 2w+1.
template <bool FUSE_MEAN>
__global__ __launch_bounds__(256) void spmm_csr_bf16(
    const int2* __restrict__ csr, const int* __restrict__ rowptr, int E,
    const ushort* __restrict__ xbf,
    const float* __restrict__ sym, const float* __restrict__ herb,
    const ushort* __restrict__ e1bf,
    void* __restrict__ outp)
{
    int wave = blockIdx.x * 4 + (threadIdx.x >> 6);
    int half = (threadIdx.x >> 5) & 1;
    int lane = threadIdx.x & 31;
    int r = wave * 2 + half;
    if (r >= N_NODES) return;

    int j   = rowptr[r];
    int end = (r + 1 < N_NODES) ? rowptr[r + 1] : E;

    float4 acc = make_float4(0.f, 0.f, 0.f, 0.f);
    for (; j + 1 < end; j += 2) {
        int2 r0 = csr[j];
        int2 r1 = csr[j + 1];
        float v0 = __int_as_float(r0.y);
        float v1 = __int_as_float(r1.y);
        ushort4 m0 = reinterpret_cast<const ushort4*>(xbf + (size_t)r0.x * DIM)[lane];
        ushort4 m1 = reinterpret_cast<const ushort4*>(xbf + (size_t)r1.x * DIM)[lane];
        acc.x += v0 * bf2f(m0.x) + v1 * bf2f(m1.x);
        acc.y += v0 * bf2f(m0.y) + v1 * bf2f(m1.y);
        acc.z += v0 * bf2f(m0.z) + v1 * bf2f(m1.z);
        acc.w += v0 * bf2f(m0.w) + v1 * bf2f(m1.w);
    }
    if (j < end) {
        int2 r0 = csr[j];
        float v0 = __int_as_float(r0.y);
        ushort4 m0 = reinterpret_cast<const ushort4*>(xbf + (size_t)r0.x * DIM)[lane];
        acc.x += v0 * bf2f(m0.x);
        acc.y += v0 * bf2f(m0.y);
        acc.z += v0 * bf2f(m0.z);
        acc.w += v0 * bf2f(m0.w);
    }

    if (FUSE_MEAN) {
        const float4* egorow = (r < NUM_SYM)
            ? reinterpret_cast<const float4*>(sym  + (size_t)r * DIM)
            : reinterpret_cast<const float4*>(herb + (size_t)(r - NUM_SYM) * DIM);
        float4 g = egorow[lane];
        ushort4 a = reinterpret_cast<const ushort4*>(e1bf + (size_t)r * DIM)[lane];
        const float s = 1.0f / 3.0f;
        acc.x = (g.x + bf2f(a.x) + acc.x) * s;
        acc.y = (g.y + bf2f(a.y) + acc.y) * s;
        acc.z = (g.z + bf2f(a.z) + acc.z) * s;
        acc.w = (g.w + bf2f(a.w) + acc.w) * s;
        reinterpret_cast<float4*>((float*)outp + (size_t)r * DIM)[lane] = acc;
    } else {
        ushort4 o;
        o.x = f2bf(acc.x); o.y = f2bf(acc.y); o.z = f2bf(acc.z); o.w = f2bf(acc.w);
        reinterpret_cast<ushort4*>((ushort*)outp + (size_t)r * DIM)[lane] = o;
    }
}

// ---------------- fallback (round-1 verified atomic path) ----------------
__global__ __launch_bounds__(256) void spmm_scatter(
    const int* __restrict__ rows, const int* __restrict__ cols,
    const float* __restrict__ vals, int n_edges,
    const float* __restrict__ xa, const float* __restrict__ xb,
    float* __restrict__ out)
{
    int gid = blockIdx.x * 256 + threadIdx.x;
    int edge = gid >> 5;
    if (edge >= n_edges) return;
    int sub = gid & 31;
    int c = cols[edge];
    int r = rows[edge];
    float v = vals[edge];
    const float* xrow = (c < NUM_SYM) ? (xa + (size_t)c * DIM)
                                      : (xb + (size_t)(c - NUM_SYM) * DIM);
    float4 m = reinterpret_cast<const float4*>(xrow)[sub];
    float* o = out + (size_t)r * DIM + (size_t)sub * 4;
    unsafeAtomicAdd(o + 0, v * m.x);
    unsafeAtomicAdd(o + 1, v * m.y);
    unsafeAtomicAdd(o + 2, v * m.z);
    unsafeAtomicAdd(o + 3, v * m.w);
}

__global__ __launch_bounds__(256) void finalize_mean(
    const float* __restrict__ sym, const float* __restrict__ herb,
    const float* __restrict__ e1, float* __restrict__ out)
{
    int i = blockIdx.x * 256 + threadIdx.x;
    const int n4 = N_NODES * DIM / 4;
    if (i >= n4) return;
    const int sym4 = NUM_SYM * DIM / 4;
    float4 e = (i < sym4) ? reinterpret_cast<const float4*>(sym)[i]
                          : reinterpret_cast<const float4*>(herb)[i - sym4];
    float4 a = reinterpret_cast<const float4*>(e1)[i];
    float4 b = reinterpret_cast<float4*>(out)[i];
    const float s = 1.0f / 3.0f;
    float4 r;
    r.x = (e.x + a.x + b.x) * s;
    r.y = (e.y + a.y + b.y) * s;
    r.z = (e.z + a.z + b.z) * s;
    r.w = (e.w + a.w + b.w) * s;
    reinterpret_cast<float4*>(out)[i] = r;
}

extern "C" void kernel_launch(void* const* d_in, const int* in_sizes, int n_in,
                              void* d_out, int out_size, void* d_ws, size_t ws_size,
                              hipStream_t stream) {
    const float* sym  = (const float*)d_in[0];
    const float* herb = (const float*)d_in[1];
    const int*   rows = (const int*)d_in[2];
    const int*   cols = (const int*)d_in[3];
    const float* vals = (const float*)d_in[4];
    const int E = in_sizes[2];
    float* out = (float*)d_out;

    // workspace layout:
    //   xbf [25.6MB] | csr [E*8] | bucketed (aliased by e1bf after k4) |
    //   rowptr [400KB] | bucket_cnt | bucket_off | cursor
    char* ws = (char*)d_ws;
    auto align256 = [](size_t x) { return (x + 255) & ~(size_t)255; };
    const size_t xbf_bytes   = (size_t)N_NODES * DIM * sizeof(ushort);   // 25.6 MB
    const size_t csr_off     = align256(xbf_bytes);
    const size_t buck_off    = align256(csr_off + (size_t)E * 8);
    const size_t buck_bytes  = (size_t)E * 8 > xbf_bytes ? (size_t)E * 8 : xbf_bytes;
    const size_t rowptr_off  = align256(buck_off + buck_bytes);
    const size_t bcnt_off    = align256(rowptr_off + (size_t)N_NODES * 4);
    const size_t boff_off    = align256(bcnt_off + (size_t)NB_BUCKETS * 4);
    const size_t bcur_off    = align256(boff_off + (size_t)(NB_BUCKETS + 1) * 4);
    const size_t required    = bcur_off + (size_t)NB_BUCKETS * 4;

    if (ws_size < required) {
        // fallback: verified round-1 atomic-scatter path (needs only 51.2MB e1)
        float* e1 = (float*)ws;
        const size_t e1_bytes = (size_t)N_NODES * DIM * sizeof(float);
        hipMemsetAsync(e1, 0, e1_bytes, stream);
        hipMemsetAsync(out, 0, e1_bytes, stream);
        const int spmm_blocks = (E * 32 + 255) / 256;
        spmm_scatter<<<spmm_blocks, 256, 0, stream>>>(rows, cols, vals, E, sym, herb, e1);
        spmm_scatter<<<spmm_blocks, 256, 0, stream>>>(rows, cols, vals, E,
                                                      e1, e1 + (size_t)NUM_SYM * DIM, out);
        const int n4 = N_NODES * DIM / 4;
        finalize_mean<<<(n4 + 255) / 256, 256, 0, stream>>>(sym, herb, e1, out);
        return;
    }

    ushort* xbf      = (ushort*)ws;
    int2*   csr      = (int2*)(ws + csr_off);
    int2*   bucketed = (int2*)(ws + buck_off);
    ushort* e1bf     = (ushort*)(ws + buck_off);   // aliases bucketed (dead after k4)
    int*    rowptr   = (int*)(ws + rowptr_off);
    int*    bcnt     = (int*)(ws + bcnt_off);
    int*    boff     = (int*)(ws + boff_off);
    int*    bcur     = (int*)(ws + bcur_off);

    // --- build row-sorted CSR via two-level bucket sort ---
    hipMemsetAsync(bcnt, 0, (size_t)NB_BUCKETS * 4, stream);
    const int EB = (E + CHUNK - 1) / CHUNK;
    hist_buckets<<<EB, 256, 0, stream>>>(rows, E, bcnt);
    scan_buckets<<<1, 512, 0, stream>>>(bcnt, boff, bcur);
    scatter_buckets<<<EB, 256, 0, stream>>>(rows, cols, vals, E, bcur, bucketed);
    bucket_to_csr<<<NB_BUCKETS, 256, 0, stream>>>(bucketed, boff, csr, rowptr);

    // --- bf16 gather table ---
    const int n4 = N_NODES * DIM / 4;
    to_bf16<<<(n4 + 255) / 256, 256, 0, stream>>>(sym, herb, xbf);

    // --- 2 propagation layers (pull over CSR) ---
    const int blocks = (N_NODES / 2 + 3) / 4;   // 2 rows/wave, 4 waves/block
    spmm_csr_bf16<false><<<blocks, 256, 0, stream>>>(csr, rowptr, E, xbf,
                                                     nullptr, nullptr, nullptr, e1bf);
    spmm_csr_bf16<true><<<blocks, 256, 0, stream>>>(csr, rowptr, E, e1bf,
                                                    sym, herb, e1bf, out);
}

// Round 7
// 472.620 us; speedup vs baseline: 1.5801x; 1.0866x over previous
//
#include <hip/hip_runtime.h>

#define NUM_SYM 50000
#define NUM_HERB 50000
#define N_NODES (NUM_SYM + NUM_HERB)
#define DIM 128
#define NB_BUCKETS ((N_NODES + 255) / 256)   // 391 coarse buckets of 256 rows
#define CHUNK 8192                           // edges per block in bucket passes
#define PAD 16                               // ints per bucket counter (64B line)

__device__ __forceinline__ float bf2f(unsigned short u) {
    return __uint_as_float((unsigned)u << 16);
}
__device__ __forceinline__ unsigned short f2bf(float f) {
    unsigned u = __float_as_uint(f);
    unsigned r = (u + 0x7FFFu + ((u >> 16) & 1u)) >> 16;   // round-to-nearest-even
    return (unsigned short)r;
}

// ---------------- bf16 staging of the gather table ----------------
__global__ __launch_bounds__(256) void to_bf16(
    const float* __restrict__ sym, const float* __restrict__ herb,
    ushort* __restrict__ xbf)
{
    int i = blockIdx.x * 256 + threadIdx.x;          // float4 index
    const int n4 = N_NODES * DIM / 4;
    if (i >= n4) return;
    const int sym4 = NUM_SYM * DIM / 4;
    float4 v = (i < sym4) ? reinterpret_cast<const float4*>(sym)[i]
                          : reinterpret_cast<const float4*>(herb)[i - sym4];
    ushort4 o;
    o.x = f2bf(v.x); o.y = f2bf(v.y); o.z = f2bf(v.z); o.w = f2bf(v.w);
    reinterpret_cast<ushort4*>(xbf)[i] = o;
}

// ---------------- two-level bucket sort (row-sorted CSR) ------------
// Bucket counters padded to one 64B line each (PAD) to avoid cross-XCD
// same-line atomic ping-pong.

// k1: coarse histogram, LDS-privatized
__global__ __launch_bounds__(256) void hist_buckets(
    const int* __restrict__ rows, int E, int* __restrict__ bucket_cnt)
{
    __shared__ int h[NB_BUCKETS];
    for (int i = threadIdx.x; i < NB_BUCKETS; i += 256) h[i] = 0;
    __syncthreads();
    int start = blockIdx.x * CHUNK;
    int end   = min(start + CHUNK, E);
    for (int e = start + threadIdx.x; e < end; e += 256)
        atomicAdd(&h[rows[e] >> 8], 1);
    __syncthreads();
    for (int i = threadIdx.x; i < NB_BUCKETS; i += 256)
        if (h[i]) atomicAdd(&bucket_cnt[i * PAD], h[i]);
}

// k2: scan 391 bucket counts -> offsets [0..NB_BUCKETS] + padded cursor
__global__ __launch_bounds__(512) void scan_buckets(
    const int* __restrict__ cnt, int* __restrict__ off, int* __restrict__ cursor)
{
    __shared__ int s[512];
    int t = threadIdx.x;
    int v = (t < NB_BUCKETS) ? cnt[t * PAD] : 0;
    s[t] = v;
    __syncthreads();
    for (int o = 1; o < 512; o <<= 1) {
        int x = (t >= o) ? s[t - o] : 0;
        __syncthreads();
        s[t] += x;
        __syncthreads();
    }
    if (t < NB_BUCKETS) { off[t] = s[t] - v; cursor[t * PAD] = s[t] - v; }
    if (t == NB_BUCKETS - 1) off[NB_BUCKETS] = s[t];
}

// k3: scatter edges into coarse buckets; one global atomicAdd per
// (block,bucket) reserves a contiguous range.
// Record: x = (row_low8 << 17) | col,  y = fp32 val bits.
__global__ __launch_bounds__(256) void scatter_buckets(
    const int* __restrict__ rows, const int* __restrict__ cols,
    const float* __restrict__ vals, int E,
    int* __restrict__ cursor, int2* __restrict__ bucketed)
{
    __shared__ int lh[NB_BUCKETS];
    __shared__ int lbase[NB_BUCKETS];
    for (int i = threadIdx.x; i < NB_BUCKETS; i += 256) lh[i] = 0;
    __syncthreads();
    int start = blockIdx.x * CHUNK;
    int end   = min(start + CHUNK, E);
    for (int e = start + threadIdx.x; e < end; e += 256)
        atomicAdd(&lh[rows[e] >> 8], 1);
    __syncthreads();
    for (int i = threadIdx.x; i < NB_BUCKETS; i += 256) {
        int c = lh[i];
        lbase[i] = c ? atomicAdd(&cursor[i * PAD], c) : 0;
        lh[i] = 0;                               // reuse as local cursor
    }
    __syncthreads();
    for (int e = start + threadIdx.x; e < end; e += 256) {
        int r = rows[e];
        int key = r >> 8;
        int pos = lbase[key] + atomicAdd(&lh[key], 1);
        bucketed[pos] = make_int2(((r & 255) << 17) | cols[e],
                                  __float_as_int(vals[e]));
    }
}

// k4: one 512-thread block per bucket -> row-sorted packed CSR + rowptr.
// CSR record (4B): (val_bf16_lo15 << 17) | col   (vals>0 so sign bit is 0)
__global__ __launch_bounds__(512) void bucket_to_csr(
    const int2* __restrict__ bucketed, const int* __restrict__ off,
    int* __restrict__ csr, int* __restrict__ rowptr)
{
    __shared__ int h[256];
    int b = blockIdx.x, t = threadIdx.x;
    int s0 = off[b], s1 = off[b + 1];
    if (t < 256) h[t] = 0;
    __syncthreads();
    for (int j = s0 + t; j < s1; j += 512)
        atomicAdd(&h[(unsigned)bucketed[j].x >> 17], 1);
    __syncthreads();
    int v = (t < 256) ? h[t] : 0;
    for (int o = 1; o < 256; o <<= 1) {          // inclusive scan (256 bins)
        int x = (t < 256 && t >= o) ? h[t - o] : 0;
        __syncthreads();
        if (t < 256) h[t] += x;
        __syncthreads();
    }
    if (t < 256) {
        int r = b * 256 + t;
        if (r < N_NODES) rowptr[r] = s0 + (h[t] - v);
    }
    __syncthreads();
    if (t < 256) h[t] -= v;                      // exclusive -> local cursor
    __syncthreads();
    for (int j = s0 + t; j < s1; j += 512) {
        int2 rec = bucketed[j];
        int key = (unsigned)rec.x >> 17;
        int pos = s0 + atomicAdd(&h[key], 1);
        unsigned vb = (unsigned)f2bf(__int_as_float(rec.y));   // sign 0, 15 bits
        csr[pos] = (int)((vb << 17) | ((unsigned)rec.x & 0x1FFFFu));
    }
}

// ---------------- pull-mode SpMM over packed CSR, bf16 gathers ----------
// 2 rows per wave: lanes 0-31 -> row 2w, lanes 32-63 -> row 2w+1.
// 4x unroll: 4 independent 256B gathers in flight per half-wave.
__device__ __forceinline__ float unpack_val(int p) {
    return __uint_as_float(((unsigned)p >> 17) << 16);
}

template <bool FUSE_MEAN>
__global__ __launch_bounds__(256) void spmm_csr_bf16(
    const int* __restrict__ csr, const int* __restrict__ rowptr, int E,
    const ushort* __restrict__ xbf,
    const float* __restrict__ sym, const float* __restrict__ herb,
    const ushort* __restrict__ e1bf,
    void* __restrict__ outp)
{
    int wave = blockIdx.x * 4 + (threadIdx.x >> 6);
    int half = (threadIdx.x >> 5) & 1;
    int lane = threadIdx.x & 31;
    int r = wave * 2 + half;
    if (r >= N_NODES) return;

    int j   = rowptr[r];
    int end = (r + 1 < N_NODES) ? rowptr[r + 1] : E;

    float4 acc = make_float4(0.f, 0.f, 0.f, 0.f);
    for (; j + 3 < end; j += 4) {
        int p0 = csr[j], p1 = csr[j + 1], p2 = csr[j + 2], p3 = csr[j + 3];
        ushort4 m0 = reinterpret_cast<const ushort4*>(xbf + (size_t)(p0 & 0x1FFFF) * DIM)[lane];
        ushort4 m1 = reinterpret_cast<const ushort4*>(xbf + (size_t)(p1 & 0x1FFFF) * DIM)[lane];
        ushort4 m2 = reinterpret_cast<const ushort4*>(xbf + (size_t)(p2 & 0x1FFFF) * DIM)[lane];
        ushort4 m3 = reinterpret_cast<const ushort4*>(xbf + (size_t)(p3 & 0x1FFFF) * DIM)[lane];
        float v0 = unpack_val(p0), v1 = unpack_val(p1);
        float v2 = unpack_val(p2), v3 = unpack_val(p3);
        acc.x += v0 * bf2f(m0.x) + v1 * bf2f(m1.x) + v2 * bf2f(m2.x) + v3 * bf2f(m3.x);
        acc.y += v0 * bf2f(m0.y) + v1 * bf2f(m1.y) + v2 * bf2f(m2.y) + v3 * bf2f(m3.y);
        acc.z += v0 * bf2f(m0.z) + v1 * bf2f(m1.z) + v2 * bf2f(m2.z) + v3 * bf2f(m3.z);
        acc.w += v0 * bf2f(m0.w) + v1 * bf2f(m1.w) + v2 * bf2f(m2.w) + v3 * bf2f(m3.w);
    }
    for (; j < end; ++j) {
        int p0 = csr[j];
        float v0 = unpack_val(p0);
        ushort4 m0 = reinterpret_cast<const ushort4*>(xbf + (size_t)(p0 & 0x1FFFF) * DIM)[lane];
        acc.x += v0 * bf2f(m0.x);
        acc.y += v0 * bf2f(m0.y);
        acc.z += v0 * bf2f(m0.z);
        acc.w += v0 * bf2f(m0.w);
    }

    if (FUSE_MEAN) {
        const float4* egorow = (r < NUM_SYM)
            ? reinterpret_cast<const float4*>(sym  + (size_t)r * DIM)
            : reinterpret_cast<const float4*>(herb + (size_t)(r - NUM_SYM) * DIM);
        float4 g = egorow[lane];
        ushort4 a = reinterpret_cast<const ushort4*>(e1bf + (size_t)r * DIM)[lane];
        const float s = 1.0f / 3.0f;
        acc.x = (g.x + bf2f(a.x) + acc.x) * s;
        acc.y = (g.y + bf2f(a.y) + acc.y) * s;
        acc.z = (g.z + bf2f(a.z) + acc.z) * s;
        acc.w = (g.w + bf2f(a.w) + acc.w) * s;
        reinterpret_cast<float4*>((float*)outp + (size_t)r * DIM)[lane] = acc;
    } else {
        ushort4 o;
        o.x = f2bf(acc.x); o.y = f2bf(acc.y); o.z = f2bf(acc.z); o.w = f2bf(acc.w);
        reinterpret_cast<ushort4*>((ushort*)outp + (size_t)r * DIM)[lane] = o;
    }
}

// ---------------- fallback (round-1 verified atomic path) ----------------
__global__ __launch_bounds__(256) void spmm_scatter(
    const int* __restrict__ rows, const int* __restrict__ cols,
    const float* __restrict__ vals, int n_edges,
    const float* __restrict__ xa, const float* __restrict__ xb,
    float* __restrict__ out)
{
    int gid = blockIdx.x * 256 + threadIdx.x;
    int edge = gid >> 5;
    if (edge >= n_edges) return;
    int sub = gid & 31;
    int c = cols[edge];
    int r = rows[edge];
    float v = vals[edge];
    const float* xrow = (c < NUM_SYM) ? (xa + (size_t)c * DIM)
                                      : (xb + (size_t)(c - NUM_SYM) * DIM);
    float4 m = reinterpret_cast<const float4*>(xrow)[sub];
    float* o = out + (size_t)r * DIM + (size_t)sub * 4;
    unsafeAtomicAdd(o + 0, v * m.x);
    unsafeAtomicAdd(o + 1, v * m.y);
    unsafeAtomicAdd(o + 2, v * m.z);
    unsafeAtomicAdd(o + 3, v * m.w);
}

__global__ __launch_bounds__(256) void finalize_mean(
    const float* __restrict__ sym, const float* __restrict__ herb,
    const float* __restrict__ e1, float* __restrict__ out)
{
    int i = blockIdx.x * 256 + threadIdx.x;
    const int n4 = N_NODES * DIM / 4;
    if (i >= n4) return;
    const int sym4 = NUM_SYM * DIM / 4;
    float4 e = (i < sym4) ? reinterpret_cast<const float4*>(sym)[i]
                          : reinterpret_cast<const float4*>(herb)[i - sym4];
    float4 a = reinterpret_cast<const float4*>(e1)[i];
    float4 b = reinterpret_cast<float4*>(out)[i];
    const float s = 1.0f / 3.0f;
    float4 r;
    r.x = (e.x + a.x + b.x) * s;
    r.y = (e.y + a.y + b.y) * s;
    r.z = (e.z + a.z + b.z) * s;
    r.w = (e.w + a.w + b.w) * s;
    reinterpret_cast<float4*>(out)[i] = r;
}

extern "C" void kernel_launch(void* const* d_in, const int* in_sizes, int n_in,
                              void* d_out, int out_size, void* d_ws, size_t ws_size,
                              hipStream_t stream) {
    const float* sym  = (const float*)d_in[0];
    const float* herb = (const float*)d_in[1];
    const int*   rows = (const int*)d_in[2];
    const int*   cols = (const int*)d_in[3];
    const float* vals = (const float*)d_in[4];
    const int E = in_sizes[2];
    float* out = (float*)d_out;

    // workspace layout:
    //   xbf [25.6MB] | csr [E*4] | bucketed [E*8] (aliased by e1bf after k4) |
    //   rowptr [400KB] | bcnt [padded] | boff | bcur [padded]
    char* ws = (char*)d_ws;
    auto align256 = [](size_t x) { return (x + 255) & ~(size_t)255; };
    const size_t xbf_bytes   = (size_t)N_NODES * DIM * sizeof(ushort);   // 25.6 MB
    const size_t csr_off     = align256(xbf_bytes);
    const size_t buck_off    = align256(csr_off + (size_t)E * 4);
    const size_t buck_bytes  = (size_t)E * 8 > xbf_bytes ? (size_t)E * 8 : xbf_bytes;
    const size_t rowptr_off  = align256(buck_off + buck_bytes);
    const size_t bcnt_off    = align256(rowptr_off + (size_t)N_NODES * 4);
    const size_t boff_off    = align256(bcnt_off + (size_t)NB_BUCKETS * PAD * 4);
    const size_t bcur_off    = align256(boff_off + (size_t)(NB_BUCKETS + 1) * 4);
    const size_t required    = bcur_off + (size_t)NB_BUCKETS * PAD * 4;

    if (ws_size < required || E >= (1 << 22)) {
        // fallback: verified round-1 atomic-scatter path (needs only 51.2MB e1)
        float* e1 = (float*)ws;
        const size_t e1_bytes = (size_t)N_NODES * DIM * sizeof(float);
        hipMemsetAsync(e1, 0, e1_bytes, stream);
        hipMemsetAsync(out, 0, e1_bytes, stream);
        const int spmm_blocks = (E * 32 + 255) / 256;
        spmm_scatter<<<spmm_blocks, 256, 0, stream>>>(rows, cols, vals, E, sym, herb, e1);
        spmm_scatter<<<spmm_blocks, 256, 0, stream>>>(rows, cols, vals, E,
                                                      e1, e1 + (size_t)NUM_SYM * DIM, out);
        const int n4 = N_NODES * DIM / 4;
        finalize_mean<<<(n4 + 255) / 256, 256, 0, stream>>>(sym, herb, e1, out);
        return;
    }

    ushort* xbf      = (ushort*)ws;
    int*    csr      = (int*)(ws + csr_off);
    int2*   bucketed = (int2*)(ws + buck_off);
    ushort* e1bf     = (ushort*)(ws + buck_off);   // aliases bucketed (dead after k4)
    int*    rowptr   = (int*)(ws + rowptr_off);
    int*    bcnt     = (int*)(ws + bcnt_off);
    int*    boff     = (int*)(ws + boff_off);
    int*    bcur     = (int*)(ws + bcur_off);

    // --- build row-sorted packed CSR via two-level bucket sort ---
    hipMemsetAsync(bcnt, 0, (size_t)NB_BUCKETS * PAD * 4, stream);
    const int EB = (E + CHUNK - 1) / CHUNK;
    hist_buckets<<<EB, 256, 0, stream>>>(rows, E, bcnt);
    scan_buckets<<<1, 512, 0, stream>>>(bcnt, boff, bcur);
    scatter_buckets<<<EB, 256, 0, stream>>>(rows, cols, vals, E, bcur, bucketed);
    bucket_to_csr<<<NB_BUCKETS, 512, 0, stream>>>(bucketed, boff, csr, rowptr);

    // --- bf16 gather table ---
    const int n4 = N_NODES * DIM / 4;
    to_bf16<<<(n4 + 255) / 256, 256, 0, stream>>>(sym, herb, xbf);

    // --- 2 propagation layers (pull over CSR) ---
    const int blocks = (N_NODES / 2 + 3) / 4;   // 2 rows/wave, 4 waves/block
    spmm_csr_bf16<false><<<blocks, 256, 0, stream>>>(csr, rowptr, E, xbf,
                                                     nullptr, nullptr, nullptr, e1bf);
    spmm_csr_bf16<true><<<blocks, 256, 0, stream>>>(csr, rowptr, E, e1bf,
                                                    sym, herb, e1bf, out);
}